// Round 11
// baseline (280.702 us; speedup 1.0000x reference)
//
#include <hip/hip_runtime.h>
#include <stdint.h>

// 7x7 conv, stride 1, pad 3, on 64 x 512 x 512 fp32 (single channel).
// out[n,y,x] = sum_{ky,kx} x[n, y+ky-3, x+kx-3] * w[ky,kx]
//
// R18: exact R10 (best measured: ~34.6us conv, total 117.6) + XCD-aware
// block swizzle (T1). Nothing else changed.
//   - R13/R17 (no-LDS streaming): 4x HBM amplification (FETCH ~200 MB,
//     WRITE ~285 MB) -> 146-156us. Eliminated. LDS staging is mandatory.
//   - 11-probe ledger: occupancy/ILP/barrier/halo/pipelining all null;
//     only real wins ever: LDS-minimal traffic + b64-not-b128 reads (R10).
//   - Remaining isolated lever: R10 dispatches y-adjacent blocks (sharing
//     6 halo rows) round-robin across XCDs -> halo re-reads miss home L2.
//     Remap l=(id&7)*512+(id>>3) (bijective, 4096=8x512; decode proven in
//     R15): each XCD owns 16 complete y-column strips; concurrent halo
//     working set ~2.6 MB < 4 MB XCD L2 -> neighbor halo = home-L2 hit.
//   - Staging (full-exec global_load_lds, wave-uniform gy guard), edge
//     path, laundered ds_read_b64 compute, FMA order, stores: byte-for-byte
//     R10 -> identical numerics (absmax 0.125).

#define IMG_W 512
#define IMG_H 512
#define NIMG  64
#define TW    256            // output tile width per block
#define TH    16             // output tile height per block
#define HALO  3
#define LDS_W 264            // floats per row: tile col c <-> global x = bx-4+c
#define LDS_H (TH + 2*HALO)  // 22 rows

// async 16B global -> LDS (dest must be uniform base + lane*16, FULL exec)
__device__ __forceinline__ void gload_lds16(const float* src, float* dst_lds)
{
    __builtin_amdgcn_global_load_lds(
        (__attribute__((address_space(1))) void*)(uintptr_t)src,
        (__attribute__((address_space(3))) void*)(uintptr_t)dst_lds,
        16, 0, 0);
}

__global__ __launch_bounds__(256, 6) void conv7x7_kernel(
    const float* __restrict__ x,
    const float* __restrict__ wgt,
    float* __restrict__ out)
{
    __shared__ float tile[LDS_H * LDS_W];   // 23,232 B, linear

    const int tid  = threadIdx.x;
    const int wave = tid >> 6;
    const int lane = tid & 63;

    // ---- XCD-aware remap (bijective: 4096 = 8 x 512). Hardware round-robins
    // consecutive ids over 8 XCDs; after remap each XCD owns 16 complete
    // y-column strips (strip = (n, x-half), ty consecutive) -> y-adjacent
    // blocks (sharing 6 halo rows) run on the same XCD, halo = home-L2 hit.
    const int id = blockIdx.x;
    const int l  = (id & 7) * 512 + (id >> 3);
    const int ty = l & 31;
    const int s  = l >> 5;
    const int bx = (s & 1) * TW;
    const int n  = s >> 1;
    const int by = ty * TH;

    const float* img = x + (size_t)n * (IMG_W * IMG_H);

    // ---- weights: wave-uniform -> SGPRs (s_loads overlap staging) ----
    float w[49];
    #pragma unroll
    for (int i = 0; i < 49; ++i) w[i] = wgt[i];

    // ---- stage interior: per row, one full wave, cols 4..259 ----
    // gx = bx + 4*lane in [bx, bx+255]: always in-bounds in x.
    // gy guard is wave-uniform -> exec stays full for every global_load_lds.
    for (int r = wave; r < LDS_H; r += 4) {
        const int gy = by - HALO + r;
        float* dst = &tile[r * LDS_W + 4 + 4 * lane];
        if ((unsigned)gy < IMG_H) {
            gload_lds16(&img[(size_t)gy * IMG_W + bx + 4 * lane], dst);
        } else {
            *(float4*)dst = make_float4(0.f, 0.f, 0.f, 0.f);  // contiguous write
        }
    }

    // ---- stage edges: 2 halo f4 per row (cols 0..3 and 260..263) ----
    if (tid < 2 * LDS_H) {
        const int r    = tid >> 1;
        const int side = tid & 1;
        const int cb   = side ? (LDS_W - 4) : 0;   // float col base in tile
        const int gx   = side ? (bx + 256) : (bx - 4);
        const int gy   = by - HALO + r;
        float4 v = make_float4(0.f, 0.f, 0.f, 0.f);
        if (((unsigned)gy < IMG_H) && ((unsigned)gx < IMG_W))
            v = *(const float4*)&img[(size_t)gy * IMG_W + gx];
        *(float4*)&tile[r * LDS_W + cb] = v;
    }

    __syncthreads();   // drains vmcnt (global_load_lds) + lgkmcnt

    // ---- compute: 4x x 4y outputs per thread, 6 ds_read_b64 per row ----
    const int lx = lane * 4;        // output x within tile
    const int rbase = wave * 4;

    // Laundered 8-byte deltas: opaque to the vectorizer -> loads stay as
    // individual ds_read_b64 (the conflict-free width), not re-merged b128.
    int d[6];
    #pragma unroll
    for (int t = 0; t < 6; ++t) {
        d[t] = t * 8;
        asm volatile("" : "+v"(d[t]));
    }

    const char* tb = (const char*)tile + (size_t)(rbase * LDS_W + lx) * 4;

    float acc[4][4] = {};

    #pragma unroll
    for (int r = 0; r < 10; ++r) {
        const char* rowb = tb + (size_t)r * (LDS_W * 4);
        float2 q[6];
        #pragma unroll
        for (int u = 0; u < 6; ++u)
            q[u] = *(const float2*)(rowb + d[u]);
        const float row[12] = {q[0].x, q[0].y, q[1].x, q[1].y,
                               q[2].x, q[2].y, q[3].x, q[3].y,
                               q[4].x, q[4].y, q[5].x, q[5].y};
        #pragma unroll
        for (int j = 0; j < 4; ++j) {
            const int ky = r - j;
            if (ky >= 0 && ky < 7) {
                #pragma unroll
                for (int kx = 0; kx < 7; ++kx) {
                    const float wv = w[ky * 7 + kx];
                    #pragma unroll
                    for (int cc = 0; cc < 4; ++cc)
                        acc[j][cc] = fmaf(row[1 + kx + cc], wv, acc[j][cc]);
                }
            }
        }
    }

    // ---- store: 4 rows of float4 per thread (contiguous per wave) ----
    float* o = out + (size_t)n * (IMG_W * IMG_H);
    #pragma unroll
    for (int j = 0; j < 4; ++j) {
        float4 v = make_float4(acc[j][0], acc[j][1], acc[j][2], acc[j][3]);
        *(float4*)&o[(size_t)(by + rbase + j) * IMG_W + bx + lx] = v;
    }
}

extern "C" void kernel_launch(void* const* d_in, const int* in_sizes, int n_in,
                              void* d_out, int out_size, void* d_ws, size_t ws_size,
                              hipStream_t stream)
{
    const float* x   = (const float*)d_in[0];
    const float* wgt = (const float*)d_in[1];
    float* out       = (float*)d_out;

    dim3 grid(4096);   // 1D; in-kernel XCD-aware remap -> (n, ty, x-half)
    conv7x7_kernel<<<grid, 256, 0, stream>>>(x, wgt, out);
}